// Round 7
// baseline (226.973 us; speedup 1.0000x reference)
//
#include <hip/hip_runtime.h>
#include <hip/hip_fp16.h>
#include <math.h>

#define NX   160
#define N2   25600        // 160*160
#define N3   4096000      // 160^3
#define NB   4

#define NBLK_XY 16000     // 5*5 tiles * 160 z * 4 b
#define TILES_PER_B 4000  // 25 * 160
#define NBLK_Z 1600       // 40 x4 * 160 y * 16 zc * 4 b / 256
#define ZCH 10            // z-chunk in conv_z

#define SA_W 52           // 48 cols + 4 pad floats
#define SB_W 36           // 32 cols + 4 pad floats

// 1D Gaussian taps exp(-d^2/50), d=-4..4 (NOT normalized, matches reference)
__device__ __constant__ float G1[9] = {
    0.72614903f, 0.83527021f, 0.92311635f, 0.98019867f, 1.0f,
    0.98019867f, 0.92311635f, 0.83527021f, 0.72614903f};

// edge sums: FULL - missing taps at low/high boundary
#define ES_FULL 7.92946852f
__device__ __constant__ float ES_M[4] = {3.46473426f, 2.48453559f, 1.56141924f,
                                         0.72614903f};
__device__ inline float edge_sum(int i) {
    float s = ES_FULL;
    if (i < 4) s -= ES_M[i];
    if (i > NX - 5) s -= ES_M[NX - 1 - i];
    return s;
}

__device__ inline float4 f4_zero() { return make_float4(0.f, 0.f, 0.f, 0.f); }
__device__ inline float4 f4_axpy(float a, float4 b, float4 c) {
    return make_float4(c.x + a * b.x, c.y + a * b.y, c.z + a * b.z, c.w + a * b.w);
}

__device__ inline float4 load_t4(const __half* p) {
    uint2 u = *(const uint2*)p;
    __half2 a = *(const __half2*)&u.x;
    __half2 b = *(const __half2*)&u.y;
    float2 fa = __half22float2(a);
    float2 fb = __half22float2(b);
    return make_float4(fa.x, fa.y, fb.x, fb.y);
}

// block = 256 threads (4 waves). Reduce NV doubles, plain store to dst
// (global OR lds). NO atomics, NO fences (R4: fences+tickets cost ~600us).
template <int NV>
__device__ inline void block_reduce_store(double* vals, double* dst) {
    __shared__ double red[4][NV];
    int lane = threadIdx.x & 63;
    int wave = threadIdx.x >> 6;
#pragma unroll
    for (int v = 0; v < NV; ++v) {
        double x = vals[v];
#pragma unroll
        for (int off = 32; off > 0; off >>= 1) x += __shfl_down(x, off, 64);
        if (lane == 0) red[wave][v] = x;
    }
    __syncthreads();
    if (threadIdx.x < NV) {
        int v = threadIdx.x;
        dst[v] = red[0][v] + red[1][v] + red[2][v] + red[3][v];
    }
}

// R3-structure: LDS-staged labels (sA), x-conv -> sB, y-conv -> fp16 t.
// 16000 small blocks (measured best granularity). Fused per-batch partial
// sums (sum p, sum in*p, sum in) -> pS[bid*3+v].
__global__ __launch_bounds__(256) void conv_xy_kernel(
    const float* __restrict__ labels, const float* __restrict__ inputs,
    __half* __restrict__ t, double* __restrict__ pS) {
    __shared__ float sA[40 * SA_W];
    __shared__ float sB[40 * SB_W];

    int bid = blockIdx.x;
    int tileX = bid % 5;
    int tileY = (bid / 5) % 5;
    int zb = bid / 25;            // z + 160*b
    int sliceOff = zb * N2;       // == b*N3 + z*N2
    int x0 = tileX * 32, y0 = tileY * 32;
    int tid = threadIdx.x;

    // load 40 rows x 12 float4, zero-padded outside the volume
    for (int i = tid; i < 480; i += 256) {
        int row = i / 12, c = i % 12;
        int gx = x0 - 8 + 4 * c;
        int gy = y0 - 4 + row;
        float4 v = f4_zero();
        if (gy >= 0 && gy < NX && gx >= 0 && gx <= NX - 4)
            v = *(const float4*)&labels[sliceOff + gy * NX + gx];
        *(float4*)&sA[row * SA_W + 4 * c] = v;
    }
    __syncthreads();

    // x-conv: 40 rows x 8 float4 outputs
    for (int i = tid; i < 320; i += 256) {
        int r = i >> 3, x4 = i & 7;
        const float* row = &sA[r * SA_W + 4 * x4];
        float4 a = *(const float4*)&row[4];
        float4 b = *(const float4*)&row[8];
        float4 c = *(const float4*)&row[12];
        float w[12] = {a.x, a.y, a.z, a.w, b.x, b.y, b.z, b.w,
                       c.x, c.y, c.z, c.w};
        float4 o = f4_zero();
#pragma unroll
        for (int d = 0; d < 9; ++d) {
            float g = G1[d];
            o.x += g * w[d];
            o.y += g * w[d + 1];
            o.z += g * w[d + 2];
            o.w += g * w[d + 3];
        }
        *(float4*)&sB[r * SB_W + 4 * x4] = o;
    }
    __syncthreads();

    // y-conv: one float4 output per thread + fp16 store + fused sums
    int oy = tid >> 3, x4 = tid & 7;
    float4 acc = f4_zero();
#pragma unroll
    for (int d = 0; d < 9; ++d) {
        float4 v = *(const float4*)&sB[(oy + d) * SB_W + 4 * x4];
        acc = f4_axpy(G1[d], v, acc);
    }
    int gi = sliceOff + (y0 + oy) * NX + (x0 + 4 * x4);
    __half2 ha = __floats2half2_rn(acc.x, acc.y);
    __half2 hb = __floats2half2_rn(acc.z, acc.w);
    uint2 u;
    u.x = *(unsigned int*)&ha;
    u.y = *(unsigned int*)&hb;
    *(uint2*)&t[gi] = u;   // byte addr 2*gi, gi%4==0 -> 8B aligned

    float4 p = *(const float4*)&sA[(oy + 4) * SA_W + 4 * x4 + 8];
    float4 in = *(const float4*)&inputs[gi];
    double vals[3];
    vals[0] = (double)(p.x + p.y + p.z + p.w);
    vals[1] = (double)(in.x * p.x + in.y * p.y + in.z * p.z + in.w * p.w);
    vals[2] = (double)(in.x + in.y + in.z + in.w);
    block_reduce_store<3>(vals, pS + 3 * bid);
}

// z-conv via register sliding window (float4 = 4 x-cols), t fp16, z-chunk 10
// (1600 blocks = 2x waves vs R5). Folds the pS->S reduction in-block
// (96 KB L2-resident reads, replaces the reduce_S launch).
__global__ __launch_bounds__(256) void conv_z_kernel(
    const __half* __restrict__ t, const float* __restrict__ labels,
    const float* __restrict__ inputs, const double* __restrict__ pS,
    double* __restrict__ pZ) {
    int tid = threadIdx.x;
    int tidg = blockIdx.x * 256 + tid;  // 0 .. 409599
    int x4 = tidg % 40;           // float4 column; x = 4*x4
    int r = tidg / 40;
    int y = r % NX;
    int zc = (tidg / 6400) % 16;  // z chunk of 10 (block-uniform)
    int b = tidg / 102400;        // block-uniform

    // fold reduce_S: sum this batch's 4000x3 partials (L2-resident)
    __shared__ double Ssh[3];
    {
        double v0 = 0, v1 = 0, v2 = 0;
        for (int i = tid; i < TILES_PER_B; i += 256) {
            const double* p = pS + 3 * (b * TILES_PER_B + i);
            v0 += p[0]; v1 += p[1]; v2 += p[2];
        }
        double vals[3] = {v0, v1, v2};
        block_reduce_store<3>(vals, Ssh);
        __syncthreads();
    }
    double sp = Ssh[0], sip = Ssh[1], si = Ssh[2];
    const double Nv = (double)N3;
    float m0 = (float)((sip / Nv) / (sp / Nv + 1e-5));
    float m1 = (float)(((si - sip) / Nv) / ((Nv - sp) / Nv + 1e-5));

    int x = x4 * 4;
    float ey = edge_sum(y);
    float cx[4] = {edge_sum(x) * ey, edge_sum(x + 1) * ey,
                   edge_sum(x + 2) * ey, edge_sum(x + 3) * ey};

    int z0 = zc * ZCH;
    int base = b * N3 + y * NX + x;

    float4 win[9];
#pragma unroll
    for (int d = 0; d < 9; ++d) {
        int z = z0 - 4 + d;
        win[d] = (z >= 0 && z < NX) ? load_t4(&t[base + z * N2]) : f4_zero();
    }

    float n0 = 0.f, d0 = 0.f, n1 = 0.f, d1 = 0.f;
#pragma unroll
    for (int g = 0; g < 2; ++g) {
        int zg = z0 + 5 * g;
        float4 tn[5], pv[5], iv[5];
#pragma unroll
        for (int j = 0; j < 5; ++j) {
            int zl = zg + j + 5;
            tn[j] = (zl < NX) ? load_t4(&t[base + zl * N2]) : f4_zero();
            int gi = base + (zg + j) * N2;
            pv[j] = *(const float4*)&labels[gi];
            iv[j] = *(const float4*)&inputs[gi];
        }
#pragma unroll
        for (int j = 0; j < 5; ++j) {
            float4 c4 = f4_zero();
#pragma unroll
            for (int d = 0; d < 9; ++d) c4 = f4_axpy(G1[d], win[d], c4);
            float ez = edge_sum(zg + j);
            float pc[4] = {pv[j].x, pv[j].y, pv[j].z, pv[j].w};
            float ic[4] = {iv[j].x, iv[j].y, iv[j].z, iv[j].w};
            float cc[4] = {c4.x, c4.y, c4.z, c4.w};
#pragma unroll
            for (int l = 0; l < 4; ++l) {
                float c1 = cx[l] * ez - cc[l];  // conv(1-p) via conv(ones)
                float df0 = ic[l] - m0; df0 *= df0;
                float w0 = __expf(-df0 * df0);
                float df1 = ic[l] - m1; df1 *= df1;
                float w1 = __expf(-df1 * df1);
                n0 += cc[l] * pc[l] * w0;
                d0 += cc[l] * w0;
                n1 += c1 * (1.f - pc[l]) * w1;
                d1 += c1 * w1;
            }
#pragma unroll
            for (int d = 0; d < 8; ++d) win[d] = win[d + 1];
            win[8] = tn[j];
        }
    }
    double vals[4] = {(double)n0, (double)d0, (double)n1, (double)d1};
    block_reduce_store<4>(vals, pZ + 4 * blockIdx.x);
}

// single block: sum 1600 per-block partials, compute final loss
__global__ __launch_bounds__(256) void finalize_kernel(
    const double* __restrict__ pZ, float* __restrict__ out) {
    double a0 = 0, a1 = 0, a2 = 0, a3 = 0;
    for (int i = threadIdx.x; i < NBLK_Z; i += 256) {
        const double* p = &pZ[4 * i];
        a0 += p[0]; a1 += p[1]; a2 += p[2]; a3 += p[3];
    }
    __shared__ double red[4][4];
    int lane = threadIdx.x & 63;
    int wave = threadIdx.x >> 6;
    double vals[4] = {a0, a1, a2, a3};
#pragma unroll
    for (int v = 0; v < 4; ++v) {
        double x = vals[v];
#pragma unroll
        for (int off = 32; off > 0; off >>= 1) x += __shfl_down(x, off, 64);
        if (lane == 0) red[wave][v] = x;
    }
    __syncthreads();
    if (threadIdx.x == 0) {
        double acc[4];
#pragma unroll
        for (int v = 0; v < 4; ++v)
            acc[v] = red[0][v] + red[1][v] + red[2][v] + red[3][v];
        double r0 = fabs(acc[0] / (acc[1] + 1e-6));
        double r1 = fabs(acc[2] / (acc[3] + 1e-6));
        out[0] = (float)(2.0 - r0 - r1);
    }
}

extern "C" void kernel_launch(void* const* d_in, const int* in_sizes, int n_in,
                              void* d_out, int out_size, void* d_ws, size_t ws_size,
                              hipStream_t stream) {
    const float* labels = (const float*)d_in[0];
    const float* inputs = (const float*)d_in[1];
    float* out = (float*)d_out;

    // ws layout:
    //   [0)       pS : 16000*3 doubles = 384000 B
    //   [384000)  pZ : 1600*4 doubles = 51200 B
    //   [524288)  t  : 160^3 halves = 8,192,000 B
    double* pS = (double*)d_ws;
    double* pZ = (double*)((char*)d_ws + 384000);
    __half* t  = (__half*)((char*)d_ws + 524288);

    hipLaunchKernelGGL(conv_xy_kernel, dim3(NBLK_XY), dim3(256), 0, stream,
                       labels, inputs, t, pS);
    hipLaunchKernelGGL(conv_z_kernel, dim3(NBLK_Z), dim3(256), 0, stream,
                       t, labels, inputs, pS, pZ);
    hipLaunchKernelGGL(finalize_kernel, dim3(1), dim3(256), 0, stream, pZ, out);
}

// Round 9
// 208.676 us; speedup vs baseline: 1.0877x; 1.0877x over previous
//
#include <hip/hip_runtime.h>
#include <hip/hip_fp16.h>
#include <math.h>

#define NX   160
#define N2   25600        // 160*160
#define N3   4096000      // 160^3
#define NB   4

#define NBLK_XY 16000     // 5*5 tiles * 160 z * 4 b
#define TILES_PER_B 4000  // 25 * 160
#define ZCH 4             // z-chunk in conv_z (windowless)
#define NBLK_Z 4000       // 40 x4 * 160 y * 40 zc * 4 b / 256

#define SA_W 52           // 48 cols + 4 pad floats
#define SB_W 36           // 32 cols + 4 pad floats

// 1D Gaussian taps exp(-d^2/50), d=-4..4 (NOT normalized, matches reference)
__device__ __constant__ float G1[9] = {
    0.72614903f, 0.83527021f, 0.92311635f, 0.98019867f, 1.0f,
    0.98019867f, 0.92311635f, 0.83527021f, 0.72614903f};

// edge sums: FULL - missing taps at low/high boundary
#define ES_FULL 7.92946852f
__device__ __constant__ float ES_M[4] = {3.46473426f, 2.48453559f, 1.56141924f,
                                         0.72614903f};
__device__ inline float edge_sum(int i) {
    float s = ES_FULL;
    if (i < 4) s -= ES_M[i];
    if (i > NX - 5) s -= ES_M[NX - 1 - i];
    return s;
}

__device__ inline float4 f4_zero() { return make_float4(0.f, 0.f, 0.f, 0.f); }
__device__ inline float4 f4_axpy(float a, float4 b, float4 c) {
    return make_float4(c.x + a * b.x, c.y + a * b.y, c.z + a * b.z, c.w + a * b.w);
}

__device__ inline float4 h4_decode(uint2 u) {
    __half2 a = *(const __half2*)&u.x;
    __half2 b = *(const __half2*)&u.y;
    float2 fa = __half22float2(a);
    float2 fb = __half22float2(b);
    return make_float4(fa.x, fa.y, fb.x, fb.y);
}

__device__ inline uint2 h4_encode(float4 v) {
    __half2 a = __floats2half2_rn(v.x, v.y);
    __half2 b = __floats2half2_rn(v.z, v.w);
    uint2 u;
    u.x = *(unsigned int*)&a;
    u.y = *(unsigned int*)&b;
    return u;
}

// block = 256 threads (4 waves). Reduce NV doubles, plain store.
// NO atomics, NO fences (R4: fences+tickets cost ~600us).
template <int NV>
__device__ inline void block_reduce_store(double* vals, double* dst) {
    __shared__ double red[4][NV];
    int lane = threadIdx.x & 63;
    int wave = threadIdx.x >> 6;
#pragma unroll
    for (int v = 0; v < NV; ++v) {
        double x = vals[v];
#pragma unroll
        for (int off = 32; off > 0; off >>= 1) x += __shfl_down(x, off, 64);
        if (lane == 0) red[wave][v] = x;
    }
    __syncthreads();
    if (threadIdx.x < NV) {
        int v = threadIdx.x;
        dst[v] = red[0][v] + red[1][v] + red[2][v] + red[3][v];
    }
}

// LDS-staged x+y conv (R3/R7-proven structure, 16000 blocks). fp16 t only.
// Fused per-batch partial sums (sum p, sum in*p, sum in) -> pS[bid*3+v].
__global__ __launch_bounds__(256) void conv_xy_kernel(
    const float* __restrict__ labels, const float* __restrict__ inputs,
    __half* __restrict__ t, double* __restrict__ pS) {
    __shared__ float sA[40 * SA_W];
    __shared__ float sB[40 * SB_W];

    int bid = blockIdx.x;
    int tileX = bid % 5;
    int tileY = (bid / 5) % 5;
    int zb = bid / 25;            // z + 160*b
    int sliceOff = zb * N2;       // == b*N3 + z*N2
    int x0 = tileX * 32, y0 = tileY * 32;
    int tid = threadIdx.x;

    // load 40 rows x 12 float4, zero-padded outside the volume
    for (int i = tid; i < 480; i += 256) {
        int row = i / 12, c = i % 12;
        int gx = x0 - 8 + 4 * c;
        int gy = y0 - 4 + row;
        float4 v = f4_zero();
        if (gy >= 0 && gy < NX && gx >= 0 && gx <= NX - 4)
            v = *(const float4*)&labels[sliceOff + gy * NX + gx];
        *(float4*)&sA[row * SA_W + 4 * c] = v;
    }
    __syncthreads();

    // x-conv: 40 rows x 8 float4 outputs
    for (int i = tid; i < 320; i += 256) {
        int r = i >> 3, x4 = i & 7;
        const float* row = &sA[r * SA_W + 4 * x4];
        float4 a = *(const float4*)&row[4];
        float4 b = *(const float4*)&row[8];
        float4 c = *(const float4*)&row[12];
        float w[12] = {a.x, a.y, a.z, a.w, b.x, b.y, b.z, b.w,
                       c.x, c.y, c.z, c.w};
        float4 o = f4_zero();
#pragma unroll
        for (int d = 0; d < 9; ++d) {
            float g = G1[d];
            o.x += g * w[d];
            o.y += g * w[d + 1];
            o.z += g * w[d + 2];
            o.w += g * w[d + 3];
        }
        *(float4*)&sB[r * SB_W + 4 * x4] = o;
    }
    __syncthreads();

    // y-conv: one float4 output per thread + fp16 store + fused sums
    int oy = tid >> 3, x4 = tid & 7;
    float4 acc = f4_zero();
#pragma unroll
    for (int d = 0; d < 9; ++d) {
        float4 v = *(const float4*)&sB[(oy + d) * SB_W + 4 * x4];
        acc = f4_axpy(G1[d], v, acc);
    }
    int gi = sliceOff + (y0 + oy) * NX + (x0 + 4 * x4);
    *(uint2*)&t[gi] = h4_encode(acc);   // byte addr 2*gi, 8B aligned

    float4 p = *(const float4*)&sA[(oy + 4) * SA_W + 4 * x4 + 8];
    float4 in = *(const float4*)&inputs[gi];
    double vals[3];
    vals[0] = (double)(p.x + p.y + p.z + p.w);
    vals[1] = (double)(in.x * p.x + in.y * p.y + in.z * p.z + in.w * p.w);
    vals[2] = (double)(in.x + in.y + in.z + in.w);
    block_reduce_store<3>(vals, pS + 3 * bid);
}

// one block per batch: sum 4000 per-tile partials -> S[3b+v]
__global__ __launch_bounds__(256) void reduce_S_kernel(
    const double* __restrict__ pS, double* __restrict__ S) {
    int b = blockIdx.x;
    double v0 = 0, v1 = 0, v2 = 0;
    for (int i = threadIdx.x; i < TILES_PER_B; i += 256) {
        const double* p = pS + 3 * (b * TILES_PER_B + i);
        v0 += p[0]; v1 += p[1]; v2 += p[2];
    }
    double vals[3] = {v0, v1, v2};
    block_reduce_store<3>(vals, S + 3 * b);
}

// Windowless z-conv: each thread owns 4 z-planes of one float4 x-column.
// ALL 20 loads (12 fp16 t-planes + 4 labels + 4 inputs) are independent and
// issued up front — no serial sliding-window chain (R7: latency-bound at
// occupancy 17.6%). 4000 blocks. Per-block partials -> pZ (plain store).
__global__ __launch_bounds__(256) void conv_z_kernel(
    const __half* __restrict__ t, const float* __restrict__ labels,
    const float* __restrict__ inputs, const double* __restrict__ S,
    double* __restrict__ pZ) {
    int tid = threadIdx.x;
    int tidg = blockIdx.x * 256 + tid;  // 0 .. 1023999
    int x4 = tidg % 40;            // float4 column; x = 4*x4
    int y = (tidg / 40) % NX;
    int zc = (tidg / 6400) % 40;   // block-uniform (6400 = 25*256)
    int b = tidg / 256000;         // block-uniform

    // per-batch means (class 0: p, class 1: 1-p)
    double sp = S[3 * b + 0], sip = S[3 * b + 1], si = S[3 * b + 2];
    const double Nv = (double)N3;
    float m0 = (float)((sip / Nv) / (sp / Nv + 1e-5));
    float m1 = (float)(((si - sip) / Nv) / ((Nv - sp) / Nv + 1e-5));

    int x = x4 * 4;
    float ey = edge_sum(y);
    float cx[4] = {edge_sum(x) * ey, edge_sum(x + 1) * ey,
                   edge_sum(x + 2) * ey, edge_sum(x + 3) * ey};

    int z0 = zc * ZCH;
    int base = b * N3 + y * NX + x;

    // 12 t-planes (z0-4 .. z0+7) + 4 p + 4 in — all independent loads
    uint2 tr[12];
#pragma unroll
    for (int d = 0; d < 12; ++d) {
        int z = z0 - 4 + d;
        tr[d] = (z >= 0 && z < NX) ? *(const uint2*)&t[base + z * N2]
                                   : make_uint2(0u, 0u);
    }
    float4 pv[4], iv[4];
#pragma unroll
    for (int j = 0; j < 4; ++j) {
        int gi = base + (z0 + j) * N2;
        pv[j] = *(const float4*)&labels[gi];
        iv[j] = *(const float4*)&inputs[gi];
    }

    float4 tw[12];
#pragma unroll
    for (int d = 0; d < 12; ++d) tw[d] = h4_decode(tr[d]);

    float n0 = 0.f, d0 = 0.f, n1 = 0.f, d1 = 0.f;
#pragma unroll
    for (int j = 0; j < 4; ++j) {
        float4 c4 = f4_zero();
#pragma unroll
        for (int d = 0; d < 9; ++d) c4 = f4_axpy(G1[d], tw[j + d], c4);
        float ez = edge_sum(z0 + j);
        float pc[4] = {pv[j].x, pv[j].y, pv[j].z, pv[j].w};
        float ic[4] = {iv[j].x, iv[j].y, iv[j].z, iv[j].w};
        float cc[4] = {c4.x, c4.y, c4.z, c4.w};
#pragma unroll
        for (int l = 0; l < 4; ++l) {
            float c1 = cx[l] * ez - cc[l];  // conv(1-p) via conv(ones)
            float df0 = ic[l] - m0; df0 *= df0;
            float w0 = __expf(-df0 * df0);
            float df1 = ic[l] - m1; df1 *= df1;
            float w1 = __expf(-df1 * df1);
            n0 += cc[l] * pc[l] * w0;
            d0 += cc[l] * w0;
            n1 += c1 * (1.f - pc[l]) * w1;
            d1 += c1 * w1;
        }
    }
    double vals[4] = {(double)n0, (double)d0, (double)n1, (double)d1};
    block_reduce_store<4>(vals, pZ + 4 * blockIdx.x);
}

// single block: sum 4000 per-block partials, compute final loss
__global__ __launch_bounds__(256) void finalize_kernel(
    const double* __restrict__ pZ, float* __restrict__ out) {
    double a0 = 0, a1 = 0, a2 = 0, a3 = 0;
    for (int i = threadIdx.x; i < NBLK_Z; i += 256) {
        const double* p = &pZ[4 * i];
        a0 += p[0]; a1 += p[1]; a2 += p[2]; a3 += p[3];
    }
    __shared__ double red[4][4];
    int lane = threadIdx.x & 63;
    int wave = threadIdx.x >> 6;
    double vals[4] = {a0, a1, a2, a3};
#pragma unroll
    for (int v = 0; v < 4; ++v) {
        double x = vals[v];
#pragma unroll
        for (int off = 32; off > 0; off >>= 1) x += __shfl_down(x, off, 64);
        if (lane == 0) red[wave][v] = x;
    }
    __syncthreads();
    if (threadIdx.x == 0) {
        double acc[4];
#pragma unroll
        for (int v = 0; v < 4; ++v)
            acc[v] = red[0][v] + red[1][v] + red[2][v] + red[3][v];
        double r0 = fabs(acc[0] / (acc[1] + 1e-6));
        double r1 = fabs(acc[2] / (acc[3] + 1e-6));
        out[0] = (float)(2.0 - r0 - r1);
    }
}

extern "C" void kernel_launch(void* const* d_in, const int* in_sizes, int n_in,
                              void* d_out, int out_size, void* d_ws, size_t ws_size,
                              hipStream_t stream) {
    const float* labels = (const float*)d_in[0];
    const float* inputs = (const float*)d_in[1];
    float* out = (float*)d_out;

    // ws layout — total 33,292,288 B, within the R2-proven 66,060,288 B:
    //   [0)       pS : 16000*3 doubles = 384,000 B
    //   [384000)  S  : 12 doubles
    //   [384096)  pZ : 4000*4 doubles = 128,000 B  (ends 512,096)
    //   [524288)  t  : 4*160^3 halves = 32,768,000 B  (R8 bug: was sized 1/4)
    double* pS = (double*)d_ws;
    double* S  = (double*)((char*)d_ws + 384000);
    double* pZ = (double*)((char*)d_ws + 384096);
    __half* t  = (__half*)((char*)d_ws + 524288);

    hipLaunchKernelGGL(conv_xy_kernel, dim3(NBLK_XY), dim3(256), 0, stream,
                       labels, inputs, t, pS);
    hipLaunchKernelGGL(reduce_S_kernel, dim3(NB), dim3(256), 0, stream, pS, S);
    hipLaunchKernelGGL(conv_z_kernel, dim3(NBLK_Z), dim3(256), 0, stream,
                       t, labels, inputs, S, pZ);
    hipLaunchKernelGGL(finalize_kernel, dim3(1), dim3(256), 0, stream, pZ, out);
}